// Round 6
// baseline (311.654 us; speedup 1.0000x reference)
//
#include <hip/hip_runtime.h>
#include <hip/hip_bf16.h>
#include <stdint.h>
#include <math.h>

// Problem constants
#define BB 4
#define NN 2048
#define DD 1024
#define HH 16
#define HDD 64
#define SS 11

#define D4_0 0.4829629131445341f
#define D4_1 0.8365163037378079f
#define D4_2 0.2241438680420134f
#define D4_3 (-0.1294095225512604f)

typedef __bf16 bf16_t;
typedef __bf16 bf16x4_t __attribute__((ext_vector_type(4)));
typedef __bf16 bf16x8_t __attribute__((ext_vector_type(8)));
typedef float f32x4_t __attribute__((ext_vector_type(4)));

// ---------------- fused f32 -> bf16 conversion ----------------
// ranges (float4 units): x 2097152 | Wqkv rows 1024..3071 (Wk,Wv) 524288 | Wg 262144 | Wo 262144
__global__ __launch_bounds__(256) void cvt_all_k(const float* __restrict__ s0,
                                                 const float* __restrict__ s1,
                                                 const float* __restrict__ s2,
                                                 const float* __restrict__ s3,
                                                 bf16_t* __restrict__ d0,
                                                 bf16_t* __restrict__ d1,
                                                 bf16_t* __restrict__ d2,
                                                 bf16_t* __restrict__ d3) {
  const int n0 = 2097152, n1 = 524288, n2 = 262144, n3 = 262144;
  int i = blockIdx.x * 256 + threadIdx.x;
  const float* s;
  bf16_t* d;
  if (i < n0) { s = s0; d = d0; }
  else if (i < n0 + n1) { i -= n0; s = s1; d = d1; }
  else if (i < n0 + n1 + n2) { i -= n0 + n1; s = s2; d = d2; }
  else { i -= n0 + n1 + n2; if (i >= n3) return; s = s3; d = d3; }
  f32x4_t v = ((const f32x4_t*)s)[i];
  bf16x4_t o;
  o[0] = (bf16_t)v[0]; o[1] = (bf16_t)v[1]; o[2] = (bf16_t)v[2]; o[3] = (bf16_t)v[3];
  ((bf16x4_t*)d)[i] = o;
}

// ---------------- Wl = Wqs . Wq  (fold q-projection into logit projection) ----------------
// Wlb[(h*11+s)][d] = sum_hd Wqs[s][hd] * Wqkv[h*64+hd][d]   (bf16 out, rows 176..255 zero)
// blv[h*11+s] = sum_hd Wqs[s][hd] * bqkv[h*64+hd]           (fp32, [176..255] zero)
__global__ __launch_bounds__(256) void wl_k(const float* __restrict__ Wqkv,
                                            const float* __restrict__ Wqs,
                                            const float* __restrict__ bqkv,
                                            bf16_t* __restrict__ Wlb,
                                            float* __restrict__ blv) {
  const int h = blockIdx.x;  // 0..15
  const int tid = threadIdx.x;
  const int d0 = tid * 4;
  float acc[SS][4];
#pragma unroll
  for (int s = 0; s < SS; s++)
#pragma unroll
    for (int j = 0; j < 4; j++) acc[s][j] = 0.f;
  for (int hd = 0; hd < 64; hd++) {
    f32x4_t w = *(const f32x4_t*)(Wqkv + (size_t)(h * 64 + hd) * 1024 + d0);
#pragma unroll
    for (int s = 0; s < SS; s++) {
      float qs = Wqs[s * 64 + hd];
#pragma unroll
      for (int j = 0; j < 4; j++) acc[s][j] += qs * w[j];
    }
  }
#pragma unroll
  for (int s = 0; s < SS; s++) {
    bf16x4_t o;
#pragma unroll
    for (int j = 0; j < 4; j++) o[j] = (bf16_t)acc[s][j];
    *(bf16x4_t*)(Wlb + (size_t)(h * SS + s) * 1024 + d0) = o;
  }
  if (tid < SS) {
    float b = 0.f;
    for (int hd = 0; hd < 64; hd++) b += Wqs[tid * 64 + hd] * bqkv[h * 64 + hd];
    blv[h * SS + tid] = b;
  }
  if (blockIdx.x == 0) {
    // zero-pad logit cols 176..255 (weights + bias)
    for (int i = tid; i < 80; i += 256) blv[176 + i] = 0.f;
    bf16x8_t z;
#pragma unroll
    for (int j = 0; j < 8; j++) z[j] = (bf16_t)0.f;
    bf16_t* pad = Wlb + 176ull * 1024;
    for (int i = tid; i < 80 * 1024 / 8; i += 256) ((bf16x8_t*)pad)[i] = z;
  }
}

// ---------------- async global->LDS helper ----------------
__device__ __forceinline__ void gload16(const void* g, void* l) {
  __builtin_amdgcn_global_load_lds((__attribute__((address_space(1))) void*)(void*)g,
                                   (__attribute__((address_space(3))) void*)l,
                                   16, 0, 0);
}

// ---------------- GEMM-A': C[8192,3328] = xb * Wab^T + biasA, region-fused epilogue ----
// N-regions by ntile: 0-7 k (-> kmag only), 8-15 v (bf16), 16-23 gate (sigmoid bf16),
// 24-25 logits (fp32, cols 0..175 valid).  R4 mapping: mtile = blk/26 (A-panel sharing).
__global__ __launch_bounds__(256) void gemm_a(const bf16_t* __restrict__ A,
                                              const bf16_t* __restrict__ Bw,
                                              const float* __restrict__ biasA,
                                              bf16_t* __restrict__ vb,
                                              bf16_t* __restrict__ gateb,
                                              float* __restrict__ lgf,
                                              float* __restrict__ kmagf) {
  __shared__ bf16_t As[128 * 64];
  __shared__ bf16_t Bs[128 * 64];
  const int K = 1024;

  const int tid = threadIdx.x;
  const int mtile = blockIdx.x / 26;
  const int ntile = blockIdx.x % 26;
  const int row0 = mtile << 7;
  const int col0 = ntile << 7;
  const int w = tid >> 6, lane = tid & 63;
  const int wm = w >> 1, wn = w & 1;
  const int m16 = lane & 15, quad = lane >> 4;

  f32x4_t acc[4][4];
#pragma unroll
  for (int i = 0; i < 4; i++)
#pragma unroll
    for (int jj = 0; jj < 4; jj++) acc[i][jj] = (f32x4_t){0.f, 0.f, 0.f, 0.f};

  for (int kb = 0; kb < K; kb += 64) {
    __syncthreads();
#pragma unroll
    for (int r = 0; r < 4; ++r) {
      int c = r * 256 + tid;
      int row = c >> 3, kc = c & 7;
      int swz = kc ^ (row & 7);
      const bf16_t* gpA = A + (size_t)(row0 + row) * K + kb + swz * 8;
      const bf16_t* gpB = Bw + (size_t)(col0 + row) * K + kb + swz * 8;
      bf16_t* lpA = As + (size_t)(r * 256 + (tid & 192)) * 8;
      bf16_t* lpB = Bs + (size_t)(r * 256 + (tid & 192)) * 8;
      gload16(gpA, lpA);
      gload16(gpB, lpB);
    }
    __syncthreads();

#pragma unroll
    for (int kk = 0; kk < 2; ++kk) {
      bf16x8_t af[4], bfr[4];
      const int kc = (kk << 2) + quad;
#pragma unroll
      for (int i = 0; i < 4; i++) {
        int arow = (wm << 6) + (i << 4) + m16;
        af[i] = *(const bf16x8_t*)(As + arow * 64 + ((kc ^ (arow & 7)) << 3));
        int brow = (wn << 6) + (i << 4) + m16;
        bfr[i] = *(const bf16x8_t*)(Bs + brow * 64 + ((kc ^ (brow & 7)) << 3));
      }
#pragma unroll
      for (int i = 0; i < 4; i++)
#pragma unroll
        for (int jj = 0; jj < 4; jj++)
          acc[i][jj] = __builtin_amdgcn_mfma_f32_16x16x32_bf16(af[i], bfr[jj], acc[i][jj], 0, 0, 0);
    }
  }

  const int region = ntile >> 3;  // 0:k 1:v 2:gate 3:logits
  if (region == 0) {
    // kmag: val = acc + bias; ksq = sum over the head's 64 cols (jj x m16)
    const int head = (ntile << 1) + wn;
#pragma unroll
    for (int i = 0; i < 4; i++) {
      float ps[4] = {0.f, 0.f, 0.f, 0.f};
#pragma unroll
      for (int jj = 0; jj < 4; jj++) {
        const float bval = biasA[col0 + (wn << 6) + (jj << 4) + m16];
#pragma unroll
        for (int r = 0; r < 4; r++) {
          float val = acc[i][jj][r] + bval;
          ps[r] += val * val;
        }
      }
#pragma unroll
      for (int r = 0; r < 4; r++) {
#pragma unroll
        for (int sh = 1; sh < 16; sh <<= 1) ps[r] += __shfl_xor(ps[r], sh, 64);
        if (m16 == 0) {
          const int grow = row0 + (wm << 6) + (i << 4) + (quad << 2) + r;
          kmagf[grow * 16 + head] = sqrtf(fmaxf(ps[r], 0.f));
        }
      }
    }
  } else {
#pragma unroll
    for (int i = 0; i < 4; i++) {
#pragma unroll
      for (int jj = 0; jj < 4; jj++) {
        const int grow0 = row0 + (wm << 6) + (i << 4) + (quad << 2);
        const int gcol = col0 + (wn << 6) + (jj << 4) + m16;
        const float bval = biasA[gcol];
#pragma unroll
        for (int r = 0; r < 4; r++) {
          float val = acc[i][jj][r] + bval;
          if (region == 1) {
            vb[(size_t)(grow0 + r) * 1024 + (gcol - 1024)] = (bf16_t)val;
          } else if (region == 2) {
            gateb[(size_t)(grow0 + r) * 1024 + (gcol - 2048)] =
                (bf16_t)(1.f / (1.f + __expf(-val)));
          } else {
            const int c = gcol - 3072;
            if (c < 176) lgf[(size_t)(grow0 + r) * 176 + c] = val;
          }
        }
      }
    }
  }
}

// ---------------- GEMM-B: out[M,N] = gmat * Wob^T + bo (fp32 out) ----------------
__global__ __launch_bounds__(256) void gemm_b(const bf16_t* __restrict__ A,
                                              const bf16_t* __restrict__ Bw,
                                              const float* __restrict__ bias,
                                              float* __restrict__ out,
                                              int M, int Nn, int K) {
  __shared__ bf16_t As[128 * 64];
  __shared__ bf16_t Bs[128 * 64];

  const int tid = threadIdx.x;
  const int ntiles = Nn >> 7;
  const int mtile = blockIdx.x / ntiles;
  const int ntile = blockIdx.x % ntiles;
  const int row0 = mtile << 7;
  const int col0 = ntile << 7;
  const int w = tid >> 6, lane = tid & 63;
  const int wm = w >> 1, wn = w & 1;
  const int m16 = lane & 15, quad = lane >> 4;

  f32x4_t acc[4][4];
#pragma unroll
  for (int i = 0; i < 4; i++)
#pragma unroll
    for (int jj = 0; jj < 4; jj++) acc[i][jj] = (f32x4_t){0.f, 0.f, 0.f, 0.f};

  for (int kb = 0; kb < K; kb += 64) {
    __syncthreads();
#pragma unroll
    for (int r = 0; r < 4; ++r) {
      int c = r * 256 + tid;
      int row = c >> 3, kc = c & 7;
      int swz = kc ^ (row & 7);
      const bf16_t* gpA = A + (size_t)(row0 + row) * K + kb + swz * 8;
      const bf16_t* gpB = Bw + (size_t)(col0 + row) * K + kb + swz * 8;
      bf16_t* lpA = As + (size_t)(r * 256 + (tid & 192)) * 8;
      bf16_t* lpB = Bs + (size_t)(r * 256 + (tid & 192)) * 8;
      gload16(gpA, lpA);
      gload16(gpB, lpB);
    }
    __syncthreads();

#pragma unroll
    for (int kk = 0; kk < 2; ++kk) {
      bf16x8_t af[4], bfr[4];
      const int kc = (kk << 2) + quad;
#pragma unroll
      for (int i = 0; i < 4; i++) {
        int arow = (wm << 6) + (i << 4) + m16;
        af[i] = *(const bf16x8_t*)(As + arow * 64 + ((kc ^ (arow & 7)) << 3));
        int brow = (wn << 6) + (i << 4) + m16;
        bfr[i] = *(const bf16x8_t*)(Bs + brow * 64 + ((kc ^ (brow & 7)) << 3));
      }
#pragma unroll
      for (int i = 0; i < 4; i++)
#pragma unroll
        for (int jj = 0; jj < 4; jj++)
          acc[i][jj] = __builtin_amdgcn_mfma_f32_16x16x32_bf16(af[i], bfr[jj], acc[i][jj], 0, 0, 0);
    }
  }

#pragma unroll
  for (int i = 0; i < 4; i++) {
#pragma unroll
    for (int jj = 0; jj < 4; jj++) {
      const int grow0 = row0 + (wm << 6) + (i << 4) + (quad << 2);
      const int gcol = col0 + (wn << 6) + (jj << 4) + m16;
      const float bval = bias[gcol];
#pragma unroll
      for (int r = 0; r < 4; r++)
        out[(size_t)(grow0 + r) * Nn + gcol] = acc[i][jj][r] + bval;
    }
  }
}

// ---------------- field + gains: pure BW now (v*kmag, 11-way softmax) ----------------
__global__ __launch_bounds__(256) void field_gains_k(const bf16_t* __restrict__ vb,
                                                     const float* __restrict__ lgf,
                                                     const float* __restrict__ kmagf,
                                                     const float* __restrict__ scale_gain,
                                                     bf16_t* __restrict__ fieldb,
                                                     float* __restrict__ gains) {
  const int tid = threadIdx.x;
  const int w = tid >> 6, lane = tid & 63;
  const int bn = blockIdx.x * 4 + w;  // 0..8191
  const int b = bn >> 11, n_pos = bn & 2047;

  float km = 0.f;
  if (lane < 16) km = kmagf[bn * 16 + lane];

#pragma unroll
  for (int h = 0; h < 16; h++) {
    const float kmh = __shfl(km, h, 64);
    const float v = (float)vb[(size_t)bn * 1024 + h * 64 + lane];
    fieldb[((size_t)(b * 16 + h) * 2048 + n_pos) * 64 + lane] = (bf16_t)(v * kmh);
  }

  if (lane < 16) {
    const int head = lane;
    float lg[SS];
    float mx = -1e30f;
#pragma unroll
    for (int s = 0; s < SS; s++) {
      lg[s] = lgf[(size_t)bn * 176 + head * SS + s] + scale_gain[s * 16 + head];
      mx = fmaxf(mx, lg[s]);
    }
    float se = 0.f;
#pragma unroll
    for (int s = 0; s < SS; s++) { lg[s] = __expf(lg[s] - mx); se += lg[s]; }
    const float inv = 1.f / se;
    float* gp = gains + ((size_t)(b * 16 + head) * 2048 + n_pos) * SS;
#pragma unroll
    for (int s = 0; s < SS; s++) gp[s] = lg[s] * inv;
  }
}

// ---------------- multiscale causal D4 conv, offset-collapsed ----------------
__global__ __launch_bounds__(256) void conv_k(const bf16_t* __restrict__ field,
                                              const float* __restrict__ gains,
                                              bf16_t* __restrict__ facc) {
  __shared__ float sg[32 * SS];
  const int tid = threadIdx.x;
  const int blk = blockIdx.x;
  const int bh = blk & 63;
  const int ntile = blk >> 6;          // 0..63
  const int n0 = ntile * 32;

  for (int i = tid; i < 32 * SS; i += 256)
    sg[i] = gains[((size_t)bh * 2048 + n0) * SS + i];
  __syncthreads();

  const int w = tid >> 6, lane = tid & 63;
  const int nsub = lane >> 3, c = lane & 7;
  const int ln = w * 8 + nsub;         // 0..31
  const int n = n0 + ln;
  const bf16_t* frow = field + (size_t)bh * 2048 * 64;

  float g[SS];
#pragma unroll
  for (int s = 0; s < SS; s++) g[s] = sg[ln * SS + s];

  float acc[8];
  {
    bf16x8_t f0 = *(const bf16x8_t*)(frow + (size_t)n * 64 + c * 8);
#pragma unroll
    for (int q = 0; q < 8; q++) acc[q] = D4_3 * (float)f0[q];
  }
#pragma unroll
  for (int j = 0; j < 11; j++) {
    float wgt = D4_2 * g[j];
    if (j >= 1) wgt += D4_1 * g[j - 1];
    int rr = n - (1 << j);
    float wv = rr >= 0 ? wgt : 0.f;
    rr = rr >= 0 ? rr : 0;
    bf16x8_t fv = *(const bf16x8_t*)(frow + (size_t)rr * 64 + c * 8);
#pragma unroll
    for (int q = 0; q < 8; q++) acc[q] += wv * (float)fv[q];
  }
#pragma unroll
  for (int j = 0; j < 10; j++) {
    int rr = n - (3 << j);
    float wv = rr >= 0 ? (D4_0 * g[j]) : 0.f;
    rr = rr >= 0 ? rr : 0;
    bf16x8_t fv = *(const bf16x8_t*)(frow + (size_t)rr * 64 + c * 8);
#pragma unroll
    for (int q = 0; q < 8; q++) acc[q] += wv * (float)fv[q];
  }
  bf16x8_t o;
#pragma unroll
  for (int q = 0; q < 8; q++) o[q] = (bf16_t)acc[q];
  *(bf16x8_t*)(facc + ((size_t)bh * 2048 + n) * 64 + c * 8) = o;
}

// ---------------- head coupling softmax mix + gate + bf16 cast ----------------
__global__ __launch_bounds__(1024) void couple_gate_k(const bf16_t* __restrict__ facc,
                                                      const float* __restrict__ fcoup,
                                                      const bf16_t* __restrict__ gate,
                                                      bf16_t* __restrict__ gmat) {
  __shared__ float sacc[1024];
  __shared__ float sc[256];
  __shared__ float scn[256];
  const int tid = threadIdx.x;
  const int bn = blockIdx.x;
  const int b = bn >> 11, n = bn & 2047;
  if (tid < 256) sc[tid] = fcoup[tid];
  const int i = tid >> 6, hd = tid & 63;
  sacc[tid] = (float)facc[(((size_t)(b * 16 + i)) * 2048 + n) * 64 + hd];
  __syncthreads();
  if (tid < 16) {
    float row[16];
    float mx = -1e30f;
#pragma unroll
    for (int j = 0; j < 16; j++) { row[j] = sc[tid * 16 + j]; mx = fmaxf(mx, row[j]); }
    float se = 0.f;
#pragma unroll
    for (int j = 0; j < 16; j++) { row[j] = __expf(row[j] - mx); se += row[j]; }
    float inv = 1.f / se;
#pragma unroll
    for (int j = 0; j < 16; j++) scn[tid * 16 + j] = row[j] * inv;
  }
  __syncthreads();
  float s = 0.f;
#pragma unroll
  for (int j = 0; j < 16; j++) s += scn[i * 16 + j] * sacc[j * 64 + hd];
  const float gt = (float)gate[(size_t)bn * 1024 + tid];
  gmat[(size_t)bn * 1024 + tid] = (bf16_t)(s * gt);
}

// ---------------- launch ----------------
extern "C" void kernel_launch(void* const* d_in, const int* in_sizes, int n_in,
                              void* d_out, int out_size, void* d_ws, size_t ws_size,
                              hipStream_t stream) {
  (void)in_sizes; (void)n_in; (void)out_size; (void)ws_size;
  const float* x = (const float*)d_in[0];
  const float* Wqkv = (const float*)d_in[1];
  const float* bqkv = (const float*)d_in[2];
  const float* Wo = (const float*)d_in[3];
  const float* bo = (const float*)d_in[4];
  const float* Wg = (const float*)d_in[5];
  const float* bg = (const float*)d_in[6];
  const float* scale_gain = (const float*)d_in[7];
  const float* Wqs = (const float*)d_in[8];
  const float* fcoup = (const float*)d_in[9];

  char* ws = (char*)d_ws;
  size_t off = 0;
  auto alloc = [&](size_t bytes) {
    void* p = ws + off;
    off += (bytes + 255) & ~(size_t)255;
    return p;
  };
  bf16_t* xb = (bf16_t*)alloc(8192ull * 1024 * 2);       // 16 MB
  bf16_t* Wab = (bf16_t*)alloc(3328ull * 1024 * 2);      // 6.8 MB: [Wk|Wv|Wg|Wl+pad]
  bf16_t* Wob = (bf16_t*)alloc(1024ull * 1024 * 2);      // 2 MB
  float* biasA = (float*)alloc(3328ull * 4);             // [bk|bv|bg|bl+pad]
  bf16_t* vb = (bf16_t*)alloc(8192ull * 1024 * 2);       // 16 MB
  bf16_t* gateb = (bf16_t*)alloc(8192ull * 1024 * 2);    // 16 MB
  float* lgf = (float*)alloc(8192ull * 176 * 4);         // 5.8 MB
  float* kmagf = (float*)alloc(8192ull * 16 * 4);        // 0.5 MB
  bf16_t* fieldb = (bf16_t*)alloc(8388608ull * 2);       // 16 MB
  float* gains = (float*)alloc(8192ull * 16 * SS * 4);   // 5.8 MB
  bf16_t* facc = (bf16_t*)alloc(8388608ull * 2);         // 16 MB
  bf16_t* gmat = (bf16_t*)alloc(8192ull * 1024 * 2);     // 16 MB

  // biasA: bk | bv | bg (bl filled by wl_k)
  hipMemcpyAsync(biasA, bqkv + 1024, 1024 * 4, hipMemcpyDeviceToDevice, stream);
  hipMemcpyAsync(biasA + 1024, bqkv + 2048, 1024 * 4, hipMemcpyDeviceToDevice, stream);
  hipMemcpyAsync(biasA + 2048, bg, 1024 * 4, hipMemcpyDeviceToDevice, stream);

  // conversions: x, Wk+Wv (Wqkv rows 1024..3071), Wg, Wo
  cvt_all_k<<<12288, 256, 0, stream>>>(x, Wqkv + 1048576, Wg, Wo,
                                       xb, Wab, Wab + 2048ull * 1024, Wob);

  // Wl = Wqs.Wq (+ logit bias), rows 3072..3327 of Wab
  wl_k<<<16, 256, 0, stream>>>(Wqkv, Wqs, bqkv, Wab + 3072ull * 1024, biasA + 3072);

  // GEMM-A': k-norm + v + gate + logits (M=8192, N=3328, K=1024)
  gemm_a<<<64 * 26, 256, 0, stream>>>(xb, Wab, biasA, vb, gateb, lgf, kmagf);

  // field + gains
  field_gains_k<<<2048, 256, 0, stream>>>(vb, lgf, kmagf, scale_gain, fieldb, gains);

  // multiscale conv (blk low 6 bits = bh)
  conv_k<<<4096, 256, 0, stream>>>(fieldb, gains, facc);

  // coupling + gate
  couple_gate_k<<<8192, 1024, 0, stream>>>(facc, fcoup, gateb, gmat);

  // GEMM-B: output (M=8192, N=1024, K=1024), fp32 out
  gemm_b<<<64 * 8, 256, 0, stream>>>(gmat, Wob, bo, (float*)d_out, 8192, 1024, 1024);
}

// Round 7
// 298.033 us; speedup vs baseline: 1.0457x; 1.0457x over previous
//
#include <hip/hip_runtime.h>
#include <hip/hip_bf16.h>
#include <stdint.h>
#include <math.h>

// Problem constants
#define BB 4
#define NN 2048
#define DD 1024
#define HH 16
#define HDD 64
#define SS 11

#define D4_0 0.4829629131445341f
#define D4_1 0.8365163037378079f
#define D4_2 0.2241438680420134f
#define D4_3 (-0.1294095225512604f)

typedef __bf16 bf16_t;
typedef __bf16 bf16x4_t __attribute__((ext_vector_type(4)));
typedef __bf16 bf16x8_t __attribute__((ext_vector_type(8)));
typedef float f32x4_t __attribute__((ext_vector_type(4)));

// ---------------- fused f32 -> bf16 conversion ----------------
// ranges (float4 units): x 2097152 | Wqkv rows 1024..3071 (Wk,Wv) 524288 | Wg 262144 | Wo 262144
__global__ __launch_bounds__(256) void cvt_all_k(const float* __restrict__ s0,
                                                 const float* __restrict__ s1,
                                                 const float* __restrict__ s2,
                                                 const float* __restrict__ s3,
                                                 bf16_t* __restrict__ d0,
                                                 bf16_t* __restrict__ d1,
                                                 bf16_t* __restrict__ d2,
                                                 bf16_t* __restrict__ d3) {
  const int n0 = 2097152, n1 = 524288, n2 = 262144, n3 = 262144;
  int i = blockIdx.x * 256 + threadIdx.x;
  const float* s;
  bf16_t* d;
  if (i < n0) { s = s0; d = d0; }
  else if (i < n0 + n1) { i -= n0; s = s1; d = d1; }
  else if (i < n0 + n1 + n2) { i -= n0 + n1; s = s2; d = d2; }
  else { i -= n0 + n1 + n2; if (i >= n3) return; s = s3; d = d3; }
  f32x4_t v = ((const f32x4_t*)s)[i];
  bf16x4_t o;
  o[0] = (bf16_t)v[0]; o[1] = (bf16_t)v[1]; o[2] = (bf16_t)v[2]; o[3] = (bf16_t)v[3];
  ((bf16x4_t*)d)[i] = o;
}

// ---------------- Wl = Wqs . Wq  (fold q-projection into logit projection) ----------------
__global__ __launch_bounds__(256) void wl_k(const float* __restrict__ Wqkv,
                                            const float* __restrict__ Wqs,
                                            const float* __restrict__ bqkv,
                                            bf16_t* __restrict__ Wlb,
                                            float* __restrict__ blv) {
  const int h = blockIdx.x;  // 0..15
  const int tid = threadIdx.x;
  const int d0 = tid * 4;
  float acc[SS][4];
#pragma unroll
  for (int s = 0; s < SS; s++)
#pragma unroll
    for (int j = 0; j < 4; j++) acc[s][j] = 0.f;
  for (int hd = 0; hd < 64; hd++) {
    f32x4_t w = *(const f32x4_t*)(Wqkv + (size_t)(h * 64 + hd) * 1024 + d0);
#pragma unroll
    for (int s = 0; s < SS; s++) {
      float qs = Wqs[s * 64 + hd];
#pragma unroll
      for (int j = 0; j < 4; j++) acc[s][j] += qs * w[j];
    }
  }
#pragma unroll
  for (int s = 0; s < SS; s++) {
    bf16x4_t o;
#pragma unroll
    for (int j = 0; j < 4; j++) o[j] = (bf16_t)acc[s][j];
    *(bf16x4_t*)(Wlb + (size_t)(h * SS + s) * 1024 + d0) = o;
  }
  if (tid < SS) {
    float b = 0.f;
    for (int hd = 0; hd < 64; hd++) b += Wqs[tid * 64 + hd] * bqkv[h * 64 + hd];
    blv[h * SS + tid] = b;
  }
  if (blockIdx.x == 0) {
    for (int i = tid; i < 80; i += 256) blv[176 + i] = 0.f;
    bf16x8_t z;
#pragma unroll
    for (int j = 0; j < 8; j++) z[j] = (bf16_t)0.f;
    bf16_t* pad = Wlb + 176ull * 1024;
    for (int i = tid; i < 80 * 1024 / 8; i += 256) ((bf16x8_t*)pad)[i] = z;
  }
}

// ---------------- async global->LDS helper ----------------
__device__ __forceinline__ void gload16(const void* g, void* l) {
  __builtin_amdgcn_global_load_lds((__attribute__((address_space(1))) void*)(void*)g,
                                   (__attribute__((address_space(3))) void*)l,
                                   16, 0, 0);
}

// ---------------- GEMM-A': C[8192,3328] = xb * Wab^T + biasA ----------------
// Regions by ntile: 0-7 -> kb (bf16), 8-15 -> vb (bf16), 16-23 -> gateb (sigmoid bf16),
// 24-25 -> lgf (fp32, cols<176). Uniform register-light epilogue (R6 lesson: fused
// kmag reduction cost VGPR 84->92, Occ 26->17.6 -> slower despite fewer FLOPs).
__global__ __launch_bounds__(256) void gemm_a(const bf16_t* __restrict__ A,
                                              const bf16_t* __restrict__ Bw,
                                              const float* __restrict__ biasA,
                                              bf16_t* __restrict__ kb,
                                              bf16_t* __restrict__ vb,
                                              bf16_t* __restrict__ gateb,
                                              float* __restrict__ lgf) {
  __shared__ bf16_t As[128 * 64];
  __shared__ bf16_t Bs[128 * 64];
  const int K = 1024;

  const int tid = threadIdx.x;
  const int mtile = blockIdx.x / 26;
  const int ntile = blockIdx.x % 26;
  const int row0 = mtile << 7;
  const int col0 = ntile << 7;
  const int w = tid >> 6, lane = tid & 63;
  const int wm = w >> 1, wn = w & 1;
  const int m16 = lane & 15, quad = lane >> 4;

  f32x4_t acc[4][4];
#pragma unroll
  for (int i = 0; i < 4; i++)
#pragma unroll
    for (int jj = 0; jj < 4; jj++) acc[i][jj] = (f32x4_t){0.f, 0.f, 0.f, 0.f};

  for (int kb_ = 0; kb_ < K; kb_ += 64) {
    __syncthreads();
#pragma unroll
    for (int r = 0; r < 4; ++r) {
      int c = r * 256 + tid;
      int row = c >> 3, kc = c & 7;
      int swz = kc ^ (row & 7);
      const bf16_t* gpA = A + (size_t)(row0 + row) * K + kb_ + swz * 8;
      const bf16_t* gpB = Bw + (size_t)(col0 + row) * K + kb_ + swz * 8;
      bf16_t* lpA = As + (size_t)(r * 256 + (tid & 192)) * 8;
      bf16_t* lpB = Bs + (size_t)(r * 256 + (tid & 192)) * 8;
      gload16(gpA, lpA);
      gload16(gpB, lpB);
    }
    __syncthreads();

#pragma unroll
    for (int kk = 0; kk < 2; ++kk) {
      bf16x8_t af[4], bfr[4];
      const int kc = (kk << 2) + quad;
#pragma unroll
      for (int i = 0; i < 4; i++) {
        int arow = (wm << 6) + (i << 4) + m16;
        af[i] = *(const bf16x8_t*)(As + arow * 64 + ((kc ^ (arow & 7)) << 3));
        int brow = (wn << 6) + (i << 4) + m16;
        bfr[i] = *(const bf16x8_t*)(Bs + brow * 64 + ((kc ^ (brow & 7)) << 3));
      }
#pragma unroll
      for (int i = 0; i < 4; i++)
#pragma unroll
        for (int jj = 0; jj < 4; jj++)
          acc[i][jj] = __builtin_amdgcn_mfma_f32_16x16x32_bf16(af[i], bfr[jj], acc[i][jj], 0, 0, 0);
    }
  }

  const int region = ntile >> 3;  // 0:k 1:v 2:gate 3:logits (block-uniform)
  if (region < 3) {
    bf16_t* outp = (region == 0) ? kb : (region == 1 ? vb : gateb);
    const int lc0 = col0 & 1023;  // col within the 1024-wide region
#pragma unroll
    for (int i = 0; i < 4; i++) {
#pragma unroll
      for (int jj = 0; jj < 4; jj++) {
        const int grow0 = row0 + (wm << 6) + (i << 4) + (quad << 2);
        const int coff = (wn << 6) + (jj << 4) + m16;
        const float bval = biasA[col0 + coff];
#pragma unroll
        for (int r = 0; r < 4; r++) {
          float val = acc[i][jj][r] + bval;
          if (region == 2) val = 1.f / (1.f + __expf(-val));
          outp[(size_t)(grow0 + r) * 1024 + lc0 + coff] = (bf16_t)val;
        }
      }
    }
  } else {
#pragma unroll
    for (int i = 0; i < 4; i++) {
#pragma unroll
      for (int jj = 0; jj < 4; jj++) {
        const int grow0 = row0 + (wm << 6) + (i << 4) + (quad << 2);
        const int gcol = col0 + (wn << 6) + (jj << 4) + m16;
        const float bval = biasA[gcol];
        const int c = gcol - 3072;
#pragma unroll
        for (int r = 0; r < 4; r++) {
          float val = acc[i][jj][r] + bval;
          if (c < 176) lgf[(size_t)(grow0 + r) * 176 + c] = val;
        }
      }
    }
  }
}

// ---------------- GEMM-B: out[M,N] = gmat * Wob^T + bo (fp32 out) ----------------
__global__ __launch_bounds__(256) void gemm_b(const bf16_t* __restrict__ A,
                                              const bf16_t* __restrict__ Bw,
                                              const float* __restrict__ bias,
                                              float* __restrict__ out,
                                              int M, int Nn, int K) {
  __shared__ bf16_t As[128 * 64];
  __shared__ bf16_t Bs[128 * 64];

  const int tid = threadIdx.x;
  const int ntiles = Nn >> 7;
  const int mtile = blockIdx.x / ntiles;
  const int ntile = blockIdx.x % ntiles;
  const int row0 = mtile << 7;
  const int col0 = ntile << 7;
  const int w = tid >> 6, lane = tid & 63;
  const int wm = w >> 1, wn = w & 1;
  const int m16 = lane & 15, quad = lane >> 4;

  f32x4_t acc[4][4];
#pragma unroll
  for (int i = 0; i < 4; i++)
#pragma unroll
    for (int jj = 0; jj < 4; jj++) acc[i][jj] = (f32x4_t){0.f, 0.f, 0.f, 0.f};

  for (int kb = 0; kb < K; kb += 64) {
    __syncthreads();
#pragma unroll
    for (int r = 0; r < 4; ++r) {
      int c = r * 256 + tid;
      int row = c >> 3, kc = c & 7;
      int swz = kc ^ (row & 7);
      const bf16_t* gpA = A + (size_t)(row0 + row) * K + kb + swz * 8;
      const bf16_t* gpB = Bw + (size_t)(col0 + row) * K + kb + swz * 8;
      bf16_t* lpA = As + (size_t)(r * 256 + (tid & 192)) * 8;
      bf16_t* lpB = Bs + (size_t)(r * 256 + (tid & 192)) * 8;
      gload16(gpA, lpA);
      gload16(gpB, lpB);
    }
    __syncthreads();

#pragma unroll
    for (int kk = 0; kk < 2; ++kk) {
      bf16x8_t af[4], bfr[4];
      const int kc = (kk << 2) + quad;
#pragma unroll
      for (int i = 0; i < 4; i++) {
        int arow = (wm << 6) + (i << 4) + m16;
        af[i] = *(const bf16x8_t*)(As + arow * 64 + ((kc ^ (arow & 7)) << 3));
        int brow = (wn << 6) + (i << 4) + m16;
        bfr[i] = *(const bf16x8_t*)(Bs + brow * 64 + ((kc ^ (brow & 7)) << 3));
      }
#pragma unroll
      for (int i = 0; i < 4; i++)
#pragma unroll
        for (int jj = 0; jj < 4; jj++)
          acc[i][jj] = __builtin_amdgcn_mfma_f32_16x16x32_bf16(af[i], bfr[jj], acc[i][jj], 0, 0, 0);
    }
  }

#pragma unroll
  for (int i = 0; i < 4; i++) {
#pragma unroll
    for (int jj = 0; jj < 4; jj++) {
      const int grow0 = row0 + (wm << 6) + (i << 4) + (quad << 2);
      const int gcol = col0 + (wn << 6) + (jj << 4) + m16;
      const float bval = bias[gcol];
#pragma unroll
      for (int r = 0; r < 4; r++)
        out[(size_t)(grow0 + r) * Nn + gcol] = acc[i][jj][r] + bval;
    }
  }
}

// ---------------- field + gains: MFMA kmag (R2-proven) + v*kmag + softmax ----------------
__global__ __launch_bounds__(256) void field_gains_k(const bf16_t* __restrict__ kb,
                                                     const bf16_t* __restrict__ vb,
                                                     const float* __restrict__ lgf,
                                                     const float* __restrict__ scale_gain,
                                                     bf16_t* __restrict__ fieldb,
                                                     float* __restrict__ gains) {
  __shared__ float skmag[4 * 16];
  const int tid = threadIdx.x;
  const int w = tid >> 6, lane = tid & 63;
  const int bn = blockIdx.x * 4 + w;  // 0..8191
  const int b = bn >> 11, n_pos = bn & 2047;
  const int m16 = lane & 15, quad = lane >> 4;
  const bf16_t* kp = kb + (size_t)bn * 1024;

  bf16x8_t ak[2];
#pragma unroll
  for (int it = 0; it < 2; it++)
    ak[it] = *(const bf16x8_t*)(kp + m16 * 64 + it * 32 + quad * 8);

  f32x4_t acc_k = (f32x4_t){0.f, 0.f, 0.f, 0.f};
#pragma unroll
  for (int it = 0; it < 2; it++)
    acc_k = __builtin_amdgcn_mfma_f32_16x16x32_bf16(ak[it], ak[it], acc_k, 0, 0, 0);

  // diag of K.K^T: D[m][n], m=quad*4+r, n=m16
#pragma unroll
  for (int r = 0; r < 4; r++) {
    if (m16 == quad * 4 + r) skmag[w * 16 + m16] = sqrtf(fmaxf(acc_k[r], 0.f));
  }
  __syncthreads();

#pragma unroll
  for (int h = 0; h < 16; h++) {
    const float km = skmag[w * 16 + h];
    const float v = (float)vb[(size_t)bn * 1024 + h * 64 + lane];
    fieldb[((size_t)(b * 16 + h) * 2048 + n_pos) * 64 + lane] = (bf16_t)(v * km);
  }

  if (lane < 16) {
    const int head = lane;
    float lg[SS];
    float mx = -1e30f;
#pragma unroll
    for (int s = 0; s < SS; s++) {
      lg[s] = lgf[(size_t)bn * 176 + head * SS + s] + scale_gain[s * 16 + head];
      mx = fmaxf(mx, lg[s]);
    }
    float se = 0.f;
#pragma unroll
    for (int s = 0; s < SS; s++) { lg[s] = __expf(lg[s] - mx); se += lg[s]; }
    const float inv = 1.f / se;
    float* gp = gains + ((size_t)(b * 16 + head) * 2048 + n_pos) * SS;
#pragma unroll
    for (int s = 0; s < SS; s++) gp[s] = lg[s] * inv;
  }
}

// ---------------- multiscale causal D4 conv, offset-collapsed ----------------
__global__ __launch_bounds__(256) void conv_k(const bf16_t* __restrict__ field,
                                              const float* __restrict__ gains,
                                              bf16_t* __restrict__ facc) {
  __shared__ float sg[32 * SS];
  const int tid = threadIdx.x;
  const int blk = blockIdx.x;
  const int bh = blk & 63;
  const int ntile = blk >> 6;          // 0..63
  const int n0 = ntile * 32;

  for (int i = tid; i < 32 * SS; i += 256)
    sg[i] = gains[((size_t)bh * 2048 + n0) * SS + i];
  __syncthreads();

  const int w = tid >> 6, lane = tid & 63;
  const int nsub = lane >> 3, c = lane & 7;
  const int ln = w * 8 + nsub;         // 0..31
  const int n = n0 + ln;
  const bf16_t* frow = field + (size_t)bh * 2048 * 64;

  float g[SS];
#pragma unroll
  for (int s = 0; s < SS; s++) g[s] = sg[ln * SS + s];

  float acc[8];
  {
    bf16x8_t f0 = *(const bf16x8_t*)(frow + (size_t)n * 64 + c * 8);
#pragma unroll
    for (int q = 0; q < 8; q++) acc[q] = D4_3 * (float)f0[q];
  }
#pragma unroll
  for (int j = 0; j < 11; j++) {
    float wgt = D4_2 * g[j];
    if (j >= 1) wgt += D4_1 * g[j - 1];
    int rr = n - (1 << j);
    float wv = rr >= 0 ? wgt : 0.f;
    rr = rr >= 0 ? rr : 0;
    bf16x8_t fv = *(const bf16x8_t*)(frow + (size_t)rr * 64 + c * 8);
#pragma unroll
    for (int q = 0; q < 8; q++) acc[q] += wv * (float)fv[q];
  }
#pragma unroll
  for (int j = 0; j < 10; j++) {
    int rr = n - (3 << j);
    float wv = rr >= 0 ? (D4_0 * g[j]) : 0.f;
    rr = rr >= 0 ? rr : 0;
    bf16x8_t fv = *(const bf16x8_t*)(frow + (size_t)rr * 64 + c * 8);
#pragma unroll
    for (int q = 0; q < 8; q++) acc[q] += wv * (float)fv[q];
  }
  bf16x8_t o;
#pragma unroll
  for (int q = 0; q < 8; q++) o[q] = (bf16_t)acc[q];
  *(bf16x8_t*)(facc + ((size_t)bh * 2048 + n) * 64 + c * 8) = o;
}

// ---------------- head coupling softmax mix + gate + bf16 cast ----------------
__global__ __launch_bounds__(1024) void couple_gate_k(const bf16_t* __restrict__ facc,
                                                      const float* __restrict__ fcoup,
                                                      const bf16_t* __restrict__ gate,
                                                      bf16_t* __restrict__ gmat) {
  __shared__ float sacc[1024];
  __shared__ float sc[256];
  __shared__ float scn[256];
  const int tid = threadIdx.x;
  const int bn = blockIdx.x;
  const int b = bn >> 11, n = bn & 2047;
  if (tid < 256) sc[tid] = fcoup[tid];
  const int i = tid >> 6, hd = tid & 63;
  sacc[tid] = (float)facc[(((size_t)(b * 16 + i)) * 2048 + n) * 64 + hd];
  __syncthreads();
  if (tid < 16) {
    float row[16];
    float mx = -1e30f;
#pragma unroll
    for (int j = 0; j < 16; j++) { row[j] = sc[tid * 16 + j]; mx = fmaxf(mx, row[j]); }
    float se = 0.f;
#pragma unroll
    for (int j = 0; j < 16; j++) { row[j] = __expf(row[j] - mx); se += row[j]; }
    float inv = 1.f / se;
#pragma unroll
    for (int j = 0; j < 16; j++) scn[tid * 16 + j] = row[j] * inv;
  }
  __syncthreads();
  float s = 0.f;
#pragma unroll
  for (int j = 0; j < 16; j++) s += scn[i * 16 + j] * sacc[j * 64 + hd];
  const float gt = (float)gate[(size_t)bn * 1024 + tid];
  gmat[(size_t)bn * 1024 + tid] = (bf16_t)(s * gt);
}

// ---------------- launch ----------------
extern "C" void kernel_launch(void* const* d_in, const int* in_sizes, int n_in,
                              void* d_out, int out_size, void* d_ws, size_t ws_size,
                              hipStream_t stream) {
  (void)in_sizes; (void)n_in; (void)out_size; (void)ws_size;
  const float* x = (const float*)d_in[0];
  const float* Wqkv = (const float*)d_in[1];
  const float* bqkv = (const float*)d_in[2];
  const float* Wo = (const float*)d_in[3];
  const float* bo = (const float*)d_in[4];
  const float* Wg = (const float*)d_in[5];
  const float* bg = (const float*)d_in[6];
  const float* scale_gain = (const float*)d_in[7];
  const float* Wqs = (const float*)d_in[8];
  const float* fcoup = (const float*)d_in[9];

  char* ws = (char*)d_ws;
  size_t off = 0;
  auto alloc = [&](size_t bytes) {
    void* p = ws + off;
    off += (bytes + 255) & ~(size_t)255;
    return p;
  };
  bf16_t* xb = (bf16_t*)alloc(8192ull * 1024 * 2);       // 16 MB
  bf16_t* Wab = (bf16_t*)alloc(3328ull * 1024 * 2);      // 6.8 MB: [Wk|Wv|Wg|Wl+pad]
  bf16_t* Wob = (bf16_t*)alloc(1024ull * 1024 * 2);      // 2 MB
  float* biasA = (float*)alloc(3328ull * 4);             // [bk|bv|bg|bl+pad]
  bf16_t* kbuf = (bf16_t*)alloc(8192ull * 1024 * 2);     // 16 MB
  bf16_t* vb = (bf16_t*)alloc(8192ull * 1024 * 2);       // 16 MB
  bf16_t* gateb = (bf16_t*)alloc(8192ull * 1024 * 2);    // 16 MB
  float* lgf = (float*)alloc(8192ull * 176 * 4);         // 5.8 MB
  bf16_t* fieldb = (bf16_t*)alloc(8388608ull * 2);       // 16 MB
  float* gains = (float*)alloc(8192ull * 16 * SS * 4);   // 5.8 MB
  bf16_t* facc = (bf16_t*)alloc(8388608ull * 2);         // 16 MB
  bf16_t* gmat = (bf16_t*)alloc(8192ull * 1024 * 2);     // 16 MB

  // biasA: bk | bv | bg (bl filled by wl_k)
  hipMemcpyAsync(biasA, bqkv + 1024, 1024 * 4, hipMemcpyDeviceToDevice, stream);
  hipMemcpyAsync(biasA + 1024, bqkv + 2048, 1024 * 4, hipMemcpyDeviceToDevice, stream);
  hipMemcpyAsync(biasA + 2048, bg, 1024 * 4, hipMemcpyDeviceToDevice, stream);

  // conversions: x, Wk+Wv (Wqkv rows 1024..3071), Wg, Wo
  cvt_all_k<<<12288, 256, 0, stream>>>(x, Wqkv + 1048576, Wg, Wo,
                                       xb, Wab, Wab + 2048ull * 1024, Wob);

  // Wl = Wqs.Wq (+ logit bias), rows 3072..3327 of Wab
  wl_k<<<16, 256, 0, stream>>>(Wqkv, Wqs, bqkv, Wab + 3072ull * 1024, biasA + 3072);

  // GEMM-A': k + v + gate + logits (M=8192, N=3328, K=1024)
  gemm_a<<<64 * 26, 256, 0, stream>>>(xb, Wab, biasA, kbuf, vb, gateb, lgf);

  // field + gains (MFMA kmag)
  field_gains_k<<<2048, 256, 0, stream>>>(kbuf, vb, lgf, scale_gain, fieldb, gains);

  // multiscale conv (blk low 6 bits = bh)
  conv_k<<<4096, 256, 0, stream>>>(fieldb, gains, facc);

  // coupling + gate
  couple_gate_k<<<8192, 1024, 0, stream>>>(facc, fcoup, gateb, gmat);

  // GEMM-B: output (M=8192, N=1024, K=1024), fp32 out
  gemm_b<<<64 * 8, 256, 0, stream>>>(gmat, Wob, bo, (float*)d_out, 8192, 1024, 1024);
}

// Round 8
// 294.977 us; speedup vs baseline: 1.0565x; 1.0104x over previous
//
#include <hip/hip_runtime.h>
#include <hip/hip_bf16.h>
#include <stdint.h>
#include <math.h>

// Problem constants
#define BB 4
#define NN 2048
#define DD 1024
#define HH 16
#define HDD 64
#define SS 11
#define LDC 3328  // C columns: k[0,1024) | v[1024,2048) | gate[2048,3072) | logits[3072,3248) | pad

#define D4_0 0.4829629131445341f
#define D4_1 0.8365163037378079f
#define D4_2 0.2241438680420134f
#define D4_3 (-0.1294095225512604f)

typedef __bf16 bf16_t;
typedef __bf16 bf16x4_t __attribute__((ext_vector_type(4)));
typedef __bf16 bf16x8_t __attribute__((ext_vector_type(8)));
typedef float f32x4_t __attribute__((ext_vector_type(4)));

// ---------------- fused prologue: cvt (12288 blks) + Wl fold (16) + bias assembly (1) ----
__global__ __launch_bounds__(256) void prep_k(const float* __restrict__ x,
                                              const float* __restrict__ Wqkv,
                                              const float* __restrict__ Wqs,
                                              const float* __restrict__ bqkv,
                                              const float* __restrict__ Wg,
                                              const float* __restrict__ Wo,
                                              const float* __restrict__ bg,
                                              bf16_t* __restrict__ xb,
                                              bf16_t* __restrict__ Wab,
                                              bf16_t* __restrict__ Wob,
                                              float* __restrict__ biasA) {
  const int blk = blockIdx.x;
  const int tid = threadIdx.x;
  if (blk < 12288) {
    // f32 -> bf16: x | Wk,Wv (Wqkv rows 1024..3071) | Wg | Wo
    int i = blk * 256 + tid;
    const int n0 = 2097152, n1 = 524288, n2 = 262144;
    const float* s;
    bf16_t* d;
    if (i < n0) { s = x; d = xb; }
    else if (i < n0 + n1) { i -= n0; s = Wqkv + 1048576; d = Wab; }
    else if (i < n0 + n1 + n2) { i -= n0 + n1; s = Wg; d = Wab + 2048ull * 1024; }
    else { i -= n0 + n1 + n2; s = Wo; d = Wob; }
    f32x4_t v = ((const f32x4_t*)s)[i];
    bf16x4_t o;
    o[0] = (bf16_t)v[0]; o[1] = (bf16_t)v[1]; o[2] = (bf16_t)v[2]; o[3] = (bf16_t)v[3];
    ((bf16x4_t*)d)[i] = o;
  } else if (blk < 12304) {
    // Wl[(h*11+s)][d] = sum_hd Wqs[s][hd] * Wq[h*64+hd][d]; bl likewise from bqkv
    const int h = blk - 12288;
    const int d0 = tid * 4;
    float acc[SS][4];
#pragma unroll
    for (int s = 0; s < SS; s++)
#pragma unroll
      for (int j = 0; j < 4; j++) acc[s][j] = 0.f;
    for (int hd = 0; hd < 64; hd++) {
      f32x4_t w = *(const f32x4_t*)(Wqkv + (size_t)(h * 64 + hd) * 1024 + d0);
#pragma unroll
      for (int s = 0; s < SS; s++) {
        float qs = Wqs[s * 64 + hd];
#pragma unroll
        for (int j = 0; j < 4; j++) acc[s][j] += qs * w[j];
      }
    }
    bf16_t* Wlb = Wab + 3072ull * 1024;
#pragma unroll
    for (int s = 0; s < SS; s++) {
      bf16x4_t o;
#pragma unroll
      for (int j = 0; j < 4; j++) o[j] = (bf16_t)acc[s][j];
      *(bf16x4_t*)(Wlb + (size_t)(h * SS + s) * 1024 + d0) = o;
    }
    if (tid < SS) {
      float b = 0.f;
      for (int hd = 0; hd < 64; hd++) b += Wqs[tid * 64 + hd] * bqkv[h * 64 + hd];
      biasA[3072 + h * SS + tid] = b;
    }
  } else {
    // bias assembly: bk | bv | bg, logit-bias pad, Wl pad rows (176..255 zero)
    for (int i = tid; i < 1024; i += 256) {
      biasA[i] = bqkv[1024 + i];
      biasA[1024 + i] = bqkv[2048 + i];
      biasA[2048 + i] = bg[i];
    }
    for (int i = tid; i < 80; i += 256) biasA[3072 + 176 + i] = 0.f;
    bf16x8_t z;
#pragma unroll
    for (int j = 0; j < 8; j++) z[j] = (bf16_t)0.f;
    bf16_t* pad = Wab + (3072ull + 176) * 1024;
    for (int i = tid; i < 80 * 1024 / 8; i += 256) ((bf16x8_t*)pad)[i] = z;
  }
}

// ---------------- async global->LDS helper ----------------
__device__ __forceinline__ void gload16(const void* g, void* l) {
  __builtin_amdgcn_global_load_lds((__attribute__((address_space(1))) void*)(void*)g,
                                   (__attribute__((address_space(3))) void*)l,
                                   16, 0, 0);
}

// ---------------- GEMM-A': C[8192,3328] = xb * Wab^T + biasA (single bf16 C) ----------
// R4-style uniform epilogue: one pointer, predicated sigmoid on gate cols [2048,3072).
__global__ __launch_bounds__(256) void gemm_a(const bf16_t* __restrict__ A,
                                              const bf16_t* __restrict__ Bw,
                                              const float* __restrict__ biasA,
                                              bf16_t* __restrict__ C) {
  __shared__ bf16_t As[128 * 64];
  __shared__ bf16_t Bs[128 * 64];
  const int K = 1024;

  const int tid = threadIdx.x;
  const int mtile = blockIdx.x / 26;
  const int ntile = blockIdx.x % 26;
  const int row0 = mtile << 7;
  const int col0 = ntile << 7;
  const int w = tid >> 6, lane = tid & 63;
  const int wm = w >> 1, wn = w & 1;
  const int m16 = lane & 15, quad = lane >> 4;

  f32x4_t acc[4][4];
#pragma unroll
  for (int i = 0; i < 4; i++)
#pragma unroll
    for (int jj = 0; jj < 4; jj++) acc[i][jj] = (f32x4_t){0.f, 0.f, 0.f, 0.f};

  for (int kb = 0; kb < K; kb += 64) {
    __syncthreads();
#pragma unroll
    for (int r = 0; r < 4; ++r) {
      int c = r * 256 + tid;
      int row = c >> 3, kc = c & 7;
      int swz = kc ^ (row & 7);
      const bf16_t* gpA = A + (size_t)(row0 + row) * K + kb + swz * 8;
      const bf16_t* gpB = Bw + (size_t)(col0 + row) * K + kb + swz * 8;
      bf16_t* lpA = As + (size_t)(r * 256 + (tid & 192)) * 8;
      bf16_t* lpB = Bs + (size_t)(r * 256 + (tid & 192)) * 8;
      gload16(gpA, lpA);
      gload16(gpB, lpB);
    }
    __syncthreads();

#pragma unroll
    for (int kk = 0; kk < 2; ++kk) {
      bf16x8_t af[4], bfr[4];
      const int kc = (kk << 2) + quad;
#pragma unroll
      for (int i = 0; i < 4; i++) {
        int arow = (wm << 6) + (i << 4) + m16;
        af[i] = *(const bf16x8_t*)(As + arow * 64 + ((kc ^ (arow & 7)) << 3));
        int brow = (wn << 6) + (i << 4) + m16;
        bfr[i] = *(const bf16x8_t*)(Bs + brow * 64 + ((kc ^ (brow & 7)) << 3));
      }
#pragma unroll
      for (int i = 0; i < 4; i++)
#pragma unroll
        for (int jj = 0; jj < 4; jj++)
          acc[i][jj] = __builtin_amdgcn_mfma_f32_16x16x32_bf16(af[i], bfr[jj], acc[i][jj], 0, 0, 0);
    }
  }

#pragma unroll
  for (int i = 0; i < 4; i++) {
#pragma unroll
    for (int jj = 0; jj < 4; jj++) {
      const int grow0 = row0 + (wm << 6) + (i << 4) + (quad << 2);
      const int gcol = col0 + (wn << 6) + (jj << 4) + m16;
      const float bval = biasA[gcol];
      const bool isgate = (gcol >= 2048) && (gcol < 3072);
#pragma unroll
      for (int r = 0; r < 4; r++) {
        float val = acc[i][jj][r] + bval;
        if (isgate) val = 1.f / (1.f + __expf(-val));
        C[(size_t)(grow0 + r) * LDC + gcol] = (bf16_t)val;
      }
    }
  }
}

// ---------------- GEMM-B: out[M,N] = gmat * Wob^T + bo (fp32 out) ----------------
__global__ __launch_bounds__(256) void gemm_b(const bf16_t* __restrict__ A,
                                              const bf16_t* __restrict__ Bw,
                                              const float* __restrict__ bias,
                                              float* __restrict__ out,
                                              int M, int Nn, int K) {
  __shared__ bf16_t As[128 * 64];
  __shared__ bf16_t Bs[128 * 64];

  const int tid = threadIdx.x;
  const int ntiles = Nn >> 7;
  const int mtile = blockIdx.x / ntiles;
  const int ntile = blockIdx.x % ntiles;
  const int row0 = mtile << 7;
  const int col0 = ntile << 7;
  const int w = tid >> 6, lane = tid & 63;
  const int wm = w >> 1, wn = w & 1;
  const int m16 = lane & 15, quad = lane >> 4;

  f32x4_t acc[4][4];
#pragma unroll
  for (int i = 0; i < 4; i++)
#pragma unroll
    for (int jj = 0; jj < 4; jj++) acc[i][jj] = (f32x4_t){0.f, 0.f, 0.f, 0.f};

  for (int kb = 0; kb < K; kb += 64) {
    __syncthreads();
#pragma unroll
    for (int r = 0; r < 4; ++r) {
      int c = r * 256 + tid;
      int row = c >> 3, kc = c & 7;
      int swz = kc ^ (row & 7);
      const bf16_t* gpA = A + (size_t)(row0 + row) * K + kb + swz * 8;
      const bf16_t* gpB = Bw + (size_t)(col0 + row) * K + kb + swz * 8;
      bf16_t* lpA = As + (size_t)(r * 256 + (tid & 192)) * 8;
      bf16_t* lpB = Bs + (size_t)(r * 256 + (tid & 192)) * 8;
      gload16(gpA, lpA);
      gload16(gpB, lpB);
    }
    __syncthreads();

#pragma unroll
    for (int kk = 0; kk < 2; ++kk) {
      bf16x8_t af[4], bfr[4];
      const int kc = (kk << 2) + quad;
#pragma unroll
      for (int i = 0; i < 4; i++) {
        int arow = (wm << 6) + (i << 4) + m16;
        af[i] = *(const bf16x8_t*)(As + arow * 64 + ((kc ^ (arow & 7)) << 3));
        int brow = (wn << 6) + (i << 4) + m16;
        bfr[i] = *(const bf16x8_t*)(Bs + brow * 64 + ((kc ^ (brow & 7)) << 3));
      }
#pragma unroll
      for (int i = 0; i < 4; i++)
#pragma unroll
        for (int jj = 0; jj < 4; jj++)
          acc[i][jj] = __builtin_amdgcn_mfma_f32_16x16x32_bf16(af[i], bfr[jj], acc[i][jj], 0, 0, 0);
    }
  }

#pragma unroll
  for (int i = 0; i < 4; i++) {
#pragma unroll
    for (int jj = 0; jj < 4; jj++) {
      const int grow0 = row0 + (wm << 6) + (i << 4) + (quad << 2);
      const int gcol = col0 + (wn << 6) + (jj << 4) + m16;
      const float bval = bias[gcol];
#pragma unroll
      for (int r = 0; r < 4; r++)
        out[(size_t)(grow0 + r) * Nn + gcol] = acc[i][jj][r] + bval;
    }
  }
}

// ---------------- field + gains: MFMA kmag + v*kmag + softmax (reads C) ----------------
__global__ __launch_bounds__(256) void field_gains_k(const bf16_t* __restrict__ C,
                                                     const float* __restrict__ scale_gain,
                                                     bf16_t* __restrict__ fieldb,
                                                     float* __restrict__ gains) {
  __shared__ float skmag[4 * 16];
  const int tid = threadIdx.x;
  const int w = tid >> 6, lane = tid & 63;
  const int bn = blockIdx.x * 4 + w;  // 0..8191
  const int b = bn >> 11, n_pos = bn & 2047;
  const int m16 = lane & 15, quad = lane >> 4;
  const bf16_t* cp = C + (size_t)bn * LDC;

  bf16x8_t ak[2];
#pragma unroll
  for (int it = 0; it < 2; it++)
    ak[it] = *(const bf16x8_t*)(cp + m16 * 64 + it * 32 + quad * 8);

  f32x4_t acc_k = (f32x4_t){0.f, 0.f, 0.f, 0.f};
#pragma unroll
  for (int it = 0; it < 2; it++)
    acc_k = __builtin_amdgcn_mfma_f32_16x16x32_bf16(ak[it], ak[it], acc_k, 0, 0, 0);

  // diag of K.K^T: D[m][n], m=quad*4+r, n=m16
#pragma unroll
  for (int r = 0; r < 4; r++) {
    if (m16 == quad * 4 + r) skmag[w * 16 + m16] = sqrtf(fmaxf(acc_k[r], 0.f));
  }
  __syncthreads();

#pragma unroll
  for (int h = 0; h < 16; h++) {
    const float km = skmag[w * 16 + h];
    const float v = (float)cp[1024 + h * 64 + lane];
    fieldb[((size_t)(b * 16 + h) * 2048 + n_pos) * 64 + lane] = (bf16_t)(v * km);
  }

  if (lane < 16) {
    const int head = lane;
    const bf16_t* lp = cp + 3072 + head * SS;
    float lg[SS];
    float mx = -1e30f;
#pragma unroll
    for (int s = 0; s < SS; s++) {
      lg[s] = (float)lp[s] + scale_gain[s * 16 + head];
      mx = fmaxf(mx, lg[s]);
    }
    float se = 0.f;
#pragma unroll
    for (int s = 0; s < SS; s++) { lg[s] = __expf(lg[s] - mx); se += lg[s]; }
    const float inv = 1.f / se;
    float* gp = gains + ((size_t)(b * 16 + head) * 2048 + n_pos) * SS;
#pragma unroll
    for (int s = 0; s < SS; s++) gp[s] = lg[s] * inv;
  }
}

// ---------------- multiscale causal D4 conv, offset-collapsed ----------------
__global__ __launch_bounds__(256) void conv_k(const bf16_t* __restrict__ field,
                                              const float* __restrict__ gains,
                                              bf16_t* __restrict__ facc) {
  __shared__ float sg[32 * SS];
  const int tid = threadIdx.x;
  const int blk = blockIdx.x;
  const int bh = blk & 63;
  const int ntile = blk >> 6;          // 0..63
  const int n0 = ntile * 32;

  for (int i = tid; i < 32 * SS; i += 256)
    sg[i] = gains[((size_t)bh * 2048 + n0) * SS + i];
  __syncthreads();

  const int w = tid >> 6, lane = tid & 63;
  const int nsub = lane >> 3, c = lane & 7;
  const int ln = w * 8 + nsub;         // 0..31
  const int n = n0 + ln;
  const bf16_t* frow = field + (size_t)bh * 2048 * 64;

  float g[SS];
#pragma unroll
  for (int s = 0; s < SS; s++) g[s] = sg[ln * SS + s];

  float acc[8];
  {
    bf16x8_t f0 = *(const bf16x8_t*)(frow + (size_t)n * 64 + c * 8);
#pragma unroll
    for (int q = 0; q < 8; q++) acc[q] = D4_3 * (float)f0[q];
  }
#pragma unroll
  for (int j = 0; j < 11; j++) {
    float wgt = D4_2 * g[j];
    if (j >= 1) wgt += D4_1 * g[j - 1];
    int rr = n - (1 << j);
    float wv = rr >= 0 ? wgt : 0.f;
    rr = rr >= 0 ? rr : 0;
    bf16x8_t fv = *(const bf16x8_t*)(frow + (size_t)rr * 64 + c * 8);
#pragma unroll
    for (int q = 0; q < 8; q++) acc[q] += wv * (float)fv[q];
  }
#pragma unroll
  for (int j = 0; j < 10; j++) {
    int rr = n - (3 << j);
    float wv = rr >= 0 ? (D4_0 * g[j]) : 0.f;
    rr = rr >= 0 ? rr : 0;
    bf16x8_t fv = *(const bf16x8_t*)(frow + (size_t)rr * 64 + c * 8);
#pragma unroll
    for (int q = 0; q < 8; q++) acc[q] += wv * (float)fv[q];
  }
  bf16x8_t o;
#pragma unroll
  for (int q = 0; q < 8; q++) o[q] = (bf16_t)acc[q];
  *(bf16x8_t*)(facc + ((size_t)bh * 2048 + n) * 64 + c * 8) = o;
}

// ---------------- head coupling softmax mix + gate (from C) + bf16 cast ----------------
__global__ __launch_bounds__(1024) void couple_gate_k(const bf16_t* __restrict__ facc,
                                                      const float* __restrict__ fcoup,
                                                      const bf16_t* __restrict__ C,
                                                      bf16_t* __restrict__ gmat) {
  __shared__ float sacc[1024];
  __shared__ float sc[256];
  __shared__ float scn[256];
  const int tid = threadIdx.x;
  const int bn = blockIdx.x;
  const int b = bn >> 11, n = bn & 2047;
  if (tid < 256) sc[tid] = fcoup[tid];
  const int i = tid >> 6, hd = tid & 63;
  sacc[tid] = (float)facc[(((size_t)(b * 16 + i)) * 2048 + n) * 64 + hd];
  __syncthreads();
  if (tid < 16) {
    float row[16];
    float mx = -1e30f;
#pragma unroll
    for (int j = 0; j < 16; j++) { row[j] = sc[tid * 16 + j]; mx = fmaxf(mx, row[j]); }
    float se = 0.f;
#pragma unroll
    for (int j = 0; j < 16; j++) { row[j] = __expf(row[j] - mx); se += row[j]; }
    float inv = 1.f / se;
#pragma unroll
    for (int j = 0; j < 16; j++) scn[tid * 16 + j] = row[j] * inv;
  }
  __syncthreads();
  float s = 0.f;
#pragma unroll
  for (int j = 0; j < 16; j++) s += scn[i * 16 + j] * sacc[j * 64 + hd];
  const float gt = (float)C[(size_t)bn * LDC + 2048 + tid];
  gmat[(size_t)bn * 1024 + tid] = (bf16_t)(s * gt);
}

// ---------------- launch ----------------
extern "C" void kernel_launch(void* const* d_in, const int* in_sizes, int n_in,
                              void* d_out, int out_size, void* d_ws, size_t ws_size,
                              hipStream_t stream) {
  (void)in_sizes; (void)n_in; (void)out_size; (void)ws_size;
  const float* x = (const float*)d_in[0];
  const float* Wqkv = (const float*)d_in[1];
  const float* bqkv = (const float*)d_in[2];
  const float* Wo = (const float*)d_in[3];
  const float* bo = (const float*)d_in[4];
  const float* Wg = (const float*)d_in[5];
  const float* bg = (const float*)d_in[6];
  const float* scale_gain = (const float*)d_in[7];
  const float* Wqs = (const float*)d_in[8];
  const float* fcoup = (const float*)d_in[9];

  char* ws = (char*)d_ws;
  size_t off = 0;
  auto alloc = [&](size_t bytes) {
    void* p = ws + off;
    off += (bytes + 255) & ~(size_t)255;
    return p;
  };
  bf16_t* xb = (bf16_t*)alloc(8192ull * 1024 * 2);       // 16 MB
  bf16_t* Wab = (bf16_t*)alloc(3328ull * 1024 * 2);      // 6.8 MB: [Wk|Wv|Wg|Wl+pad]
  bf16_t* Wob = (bf16_t*)alloc(1024ull * 1024 * 2);      // 2 MB
  float* biasA = (float*)alloc(3328ull * 4);             // [bk|bv|bg|bl+pad]
  bf16_t* C = (bf16_t*)alloc(8192ull * LDC * 2);         // 54.5 MB
  bf16_t* fieldb = (bf16_t*)alloc(8388608ull * 2);       // 16 MB
  float* gains = (float*)alloc(8192ull * 16 * SS * 4);   // 5.8 MB
  bf16_t* facc = (bf16_t*)alloc(8388608ull * 2);         // 16 MB
  bf16_t* gmat = (bf16_t*)alloc(8192ull * 1024 * 2);     // 16 MB

  // fused prologue: conversions + Wl fold + bias assembly
  prep_k<<<12305, 256, 0, stream>>>(x, Wqkv, Wqs, bqkv, Wg, Wo, bg, xb, Wab, Wob, biasA);

  // GEMM-A': C = xb * Wab^T + biasA (M=8192, N=3328, K=1024)
  gemm_a<<<64 * 26, 256, 0, stream>>>(xb, Wab, biasA, C);

  // field + gains (MFMA kmag, reads C)
  field_gains_k<<<2048, 256, 0, stream>>>(C, scale_gain, fieldb, gains);

  // multiscale conv (blk low 6 bits = bh)
  conv_k<<<4096, 256, 0, stream>>>(fieldb, gains, facc);

  // coupling + gate
  couple_gate_k<<<8192, 1024, 0, stream>>>(facc, fcoup, C, gmat);

  // GEMM-B: output (M=8192, N=1024, K=1024), fp32 out
  gemm_b<<<64 * 8, 256, 0, stream>>>(gmat, Wob, bo, (float*)d_out, 8192, 1024, 1024);
}

// Round 9
// 286.039 us; speedup vs baseline: 1.0895x; 1.0312x over previous
//
#include <hip/hip_runtime.h>
#include <hip/hip_bf16.h>
#include <stdint.h>
#include <math.h>

// Problem constants
#define BB 4
#define NN 2048
#define DD 1024
#define HH 16
#define HDD 64
#define SS 11
#define LDC 3328  // C columns: k[0,1024) | v[1024,2048) | gate[2048,3072) | logits[3072,3248) | pad

#define D4_0 0.4829629131445341f
#define D4_1 0.8365163037378079f
#define D4_2 0.2241438680420134f
#define D4_3 (-0.1294095225512604f)

typedef __bf16 bf16_t;
typedef __bf16 bf16x4_t __attribute__((ext_vector_type(4)));
typedef __bf16 bf16x8_t __attribute__((ext_vector_type(8)));
typedef float f32x4_t __attribute__((ext_vector_type(4)));

// ---------------- fused prologue: cvt (12288 blks) + Wl fold (16) + bias assembly (1) ----
__global__ __launch_bounds__(256) void prep_k(const float* __restrict__ x,
                                              const float* __restrict__ Wqkv,
                                              const float* __restrict__ Wqs,
                                              const float* __restrict__ bqkv,
                                              const float* __restrict__ Wg,
                                              const float* __restrict__ Wo,
                                              const float* __restrict__ bg,
                                              bf16_t* __restrict__ xb,
                                              bf16_t* __restrict__ Wab,
                                              bf16_t* __restrict__ Wob,
                                              float* __restrict__ biasA) {
  const int blk = blockIdx.x;
  const int tid = threadIdx.x;
  if (blk < 12288) {
    // f32 -> bf16: x | Wk,Wv (Wqkv rows 1024..3071) | Wg | Wo
    int i = blk * 256 + tid;
    const int n0 = 2097152, n1 = 524288, n2 = 262144;
    const float* s;
    bf16_t* d;
    if (i < n0) { s = x; d = xb; }
    else if (i < n0 + n1) { i -= n0; s = Wqkv + 1048576; d = Wab; }
    else if (i < n0 + n1 + n2) { i -= n0 + n1; s = Wg; d = Wab + 2048ull * 1024; }
    else { i -= n0 + n1 + n2; s = Wo; d = Wob; }
    f32x4_t v = ((const f32x4_t*)s)[i];
    bf16x4_t o;
    o[0] = (bf16_t)v[0]; o[1] = (bf16_t)v[1]; o[2] = (bf16_t)v[2]; o[3] = (bf16_t)v[3];
    ((bf16x4_t*)d)[i] = o;
  } else if (blk < 12304) {
    // Wl[(h*11+s)][d] = sum_hd Wqs[s][hd] * Wq[h*64+hd][d]; bl likewise from bqkv
    const int h = blk - 12288;
    const int d0 = tid * 4;
    float acc[SS][4];
#pragma unroll
    for (int s = 0; s < SS; s++)
#pragma unroll
      for (int j = 0; j < 4; j++) acc[s][j] = 0.f;
    for (int hd = 0; hd < 64; hd++) {
      f32x4_t w = *(const f32x4_t*)(Wqkv + (size_t)(h * 64 + hd) * 1024 + d0);
#pragma unroll
      for (int s = 0; s < SS; s++) {
        float qs = Wqs[s * 64 + hd];
#pragma unroll
        for (int j = 0; j < 4; j++) acc[s][j] += qs * w[j];
      }
    }
    bf16_t* Wlb = Wab + 3072ull * 1024;
#pragma unroll
    for (int s = 0; s < SS; s++) {
      bf16x4_t o;
#pragma unroll
      for (int j = 0; j < 4; j++) o[j] = (bf16_t)acc[s][j];
      *(bf16x4_t*)(Wlb + (size_t)(h * SS + s) * 1024 + d0) = o;
    }
    if (tid < SS) {
      float b = 0.f;
      for (int hd = 0; hd < 64; hd++) b += Wqs[tid * 64 + hd] * bqkv[h * 64 + hd];
      biasA[3072 + h * SS + tid] = b;
    }
  } else {
    // bias assembly: bk | bv | bg, logit-bias pad, Wl pad rows (176..255 zero)
    for (int i = tid; i < 1024; i += 256) {
      biasA[i] = bqkv[1024 + i];
      biasA[1024 + i] = bqkv[2048 + i];
      biasA[2048 + i] = bg[i];
    }
    for (int i = tid; i < 80; i += 256) biasA[3072 + 176 + i] = 0.f;
    bf16x8_t z;
#pragma unroll
    for (int j = 0; j < 8; j++) z[j] = (bf16_t)0.f;
    bf16_t* pad = Wab + (3072ull + 176) * 1024;
    for (int i = tid; i < 80 * 1024 / 8; i += 256) ((bf16x8_t*)pad)[i] = z;
  }
}

// ---------------- async global->LDS helper ----------------
__device__ __forceinline__ void gload16(const void* g, void* l) {
  __builtin_amdgcn_global_load_lds((__attribute__((address_space(1))) void*)(void*)g,
                                   (__attribute__((address_space(3))) void*)l,
                                   16, 0, 0);
}

// ---------------- GEMM-A': C[8192,3328] = xb * Wab^T + biasA (single bf16 C) ----------
// Block order: mtile FASTEST (blk = ntile*64 + mtile). With XCD = blk%8 round-robin and
// 64 ≡ 0 (mod 8), XCD = mtile%8 — stable. Each XCD keeps its 8 A-panels (2 MB) L2-resident
// across all 26 ntile bursts; each B-panel is fetched once per burst. (R6-R8 lesson:
// ntiles=26 with ntile-fastest gave XCD=(2*mtile+ntile)%8 -> B thrash, FETCH 121 MB.)
__global__ __launch_bounds__(256) void gemm_a(const bf16_t* __restrict__ A,
                                              const bf16_t* __restrict__ Bw,
                                              const float* __restrict__ biasA,
                                              bf16_t* __restrict__ C) {
  __shared__ bf16_t As[128 * 64];
  __shared__ bf16_t Bs[128 * 64];
  const int K = 1024;

  const int tid = threadIdx.x;
  const int mtile = blockIdx.x & 63;
  const int ntile = blockIdx.x >> 6;
  const int row0 = mtile << 7;
  const int col0 = ntile << 7;
  const int w = tid >> 6, lane = tid & 63;
  const int wm = w >> 1, wn = w & 1;
  const int m16 = lane & 15, quad = lane >> 4;

  f32x4_t acc[4][4];
#pragma unroll
  for (int i = 0; i < 4; i++)
#pragma unroll
    for (int jj = 0; jj < 4; jj++) acc[i][jj] = (f32x4_t){0.f, 0.f, 0.f, 0.f};

  for (int kb = 0; kb < K; kb += 64) {
    __syncthreads();
#pragma unroll
    for (int r = 0; r < 4; ++r) {
      int c = r * 256 + tid;
      int row = c >> 3, kc = c & 7;
      int swz = kc ^ (row & 7);
      const bf16_t* gpA = A + (size_t)(row0 + row) * K + kb + swz * 8;
      const bf16_t* gpB = Bw + (size_t)(col0 + row) * K + kb + swz * 8;
      bf16_t* lpA = As + (size_t)(r * 256 + (tid & 192)) * 8;
      bf16_t* lpB = Bs + (size_t)(r * 256 + (tid & 192)) * 8;
      gload16(gpA, lpA);
      gload16(gpB, lpB);
    }
    __syncthreads();

#pragma unroll
    for (int kk = 0; kk < 2; ++kk) {
      bf16x8_t af[4], bfr[4];
      const int kc = (kk << 2) + quad;
#pragma unroll
      for (int i = 0; i < 4; i++) {
        int arow = (wm << 6) + (i << 4) + m16;
        af[i] = *(const bf16x8_t*)(As + arow * 64 + ((kc ^ (arow & 7)) << 3));
        int brow = (wn << 6) + (i << 4) + m16;
        bfr[i] = *(const bf16x8_t*)(Bs + brow * 64 + ((kc ^ (brow & 7)) << 3));
      }
#pragma unroll
      for (int i = 0; i < 4; i++)
#pragma unroll
        for (int jj = 0; jj < 4; jj++)
          acc[i][jj] = __builtin_amdgcn_mfma_f32_16x16x32_bf16(af[i], bfr[jj], acc[i][jj], 0, 0, 0);
    }
  }

#pragma unroll
  for (int i = 0; i < 4; i++) {
#pragma unroll
    for (int jj = 0; jj < 4; jj++) {
      const int grow0 = row0 + (wm << 6) + (i << 4) + (quad << 2);
      const int gcol = col0 + (wn << 6) + (jj << 4) + m16;
      const float bval = biasA[gcol];
      const bool isgate = (gcol >= 2048) && (gcol < 3072);
#pragma unroll
      for (int r = 0; r < 4; r++) {
        float val = acc[i][jj][r] + bval;
        if (isgate) val = 1.f / (1.f + __expf(-val));
        C[(size_t)(grow0 + r) * LDC + gcol] = (bf16_t)val;
      }
    }
  }
}

// ---------------- GEMM-B: out[M,N] = gmat * Wob^T + bo (fp32 out) ----------------
__global__ __launch_bounds__(256) void gemm_b(const bf16_t* __restrict__ A,
                                              const bf16_t* __restrict__ Bw,
                                              const float* __restrict__ bias,
                                              float* __restrict__ out,
                                              int M, int Nn, int K) {
  __shared__ bf16_t As[128 * 64];
  __shared__ bf16_t Bs[128 * 64];

  const int tid = threadIdx.x;
  const int ntiles = Nn >> 7;
  const int mtile = blockIdx.x / ntiles;
  const int ntile = blockIdx.x % ntiles;
  const int row0 = mtile << 7;
  const int col0 = ntile << 7;
  const int w = tid >> 6, lane = tid & 63;
  const int wm = w >> 1, wn = w & 1;
  const int m16 = lane & 15, quad = lane >> 4;

  f32x4_t acc[4][4];
#pragma unroll
  for (int i = 0; i < 4; i++)
#pragma unroll
    for (int jj = 0; jj < 4; jj++) acc[i][jj] = (f32x4_t){0.f, 0.f, 0.f, 0.f};

  for (int kb = 0; kb < K; kb += 64) {
    __syncthreads();
#pragma unroll
    for (int r = 0; r < 4; ++r) {
      int c = r * 256 + tid;
      int row = c >> 3, kc = c & 7;
      int swz = kc ^ (row & 7);
      const bf16_t* gpA = A + (size_t)(row0 + row) * K + kb + swz * 8;
      const bf16_t* gpB = Bw + (size_t)(col0 + row) * K + kb + swz * 8;
      bf16_t* lpA = As + (size_t)(r * 256 + (tid & 192)) * 8;
      bf16_t* lpB = Bs + (size_t)(r * 256 + (tid & 192)) * 8;
      gload16(gpA, lpA);
      gload16(gpB, lpB);
    }
    __syncthreads();

#pragma unroll
    for (int kk = 0; kk < 2; ++kk) {
      bf16x8_t af[4], bfr[4];
      const int kc = (kk << 2) + quad;
#pragma unroll
      for (int i = 0; i < 4; i++) {
        int arow = (wm << 6) + (i << 4) + m16;
        af[i] = *(const bf16x8_t*)(As + arow * 64 + ((kc ^ (arow & 7)) << 3));
        int brow = (wn << 6) + (i << 4) + m16;
        bfr[i] = *(const bf16x8_t*)(Bs + brow * 64 + ((kc ^ (brow & 7)) << 3));
      }
#pragma unroll
      for (int i = 0; i < 4; i++)
#pragma unroll
        for (int jj = 0; jj < 4; jj++)
          acc[i][jj] = __builtin_amdgcn_mfma_f32_16x16x32_bf16(af[i], bfr[jj], acc[i][jj], 0, 0, 0);
    }
  }

#pragma unroll
  for (int i = 0; i < 4; i++) {
#pragma unroll
    for (int jj = 0; jj < 4; jj++) {
      const int grow0 = row0 + (wm << 6) + (i << 4) + (quad << 2);
      const int gcol = col0 + (wn << 6) + (jj << 4) + m16;
      const float bval = bias[gcol];
#pragma unroll
      for (int r = 0; r < 4; r++)
        out[(size_t)(grow0 + r) * Nn + gcol] = acc[i][jj][r] + bval;
    }
  }
}

// ---------------- field + gains: MFMA kmag + v*kmag + softmax (reads C) ----------------
__global__ __launch_bounds__(256) void field_gains_k(const bf16_t* __restrict__ C,
                                                     const float* __restrict__ scale_gain,
                                                     bf16_t* __restrict__ fieldb,
                                                     float* __restrict__ gains) {
  __shared__ float skmag[4 * 16];
  const int tid = threadIdx.x;
  const int w = tid >> 6, lane = tid & 63;
  const int bn = blockIdx.x * 4 + w;  // 0..8191
  const int b = bn >> 11, n_pos = bn & 2047;
  const int m16 = lane & 15, quad = lane >> 4;
  const bf16_t* cp = C + (size_t)bn * LDC;

  bf16x8_t ak[2];
#pragma unroll
  for (int it = 0; it < 2; it++)
    ak[it] = *(const bf16x8_t*)(cp + m16 * 64 + it * 32 + quad * 8);

  f32x4_t acc_k = (f32x4_t){0.f, 0.f, 0.f, 0.f};
#pragma unroll
  for (int it = 0; it < 2; it++)
    acc_k = __builtin_amdgcn_mfma_f32_16x16x32_bf16(ak[it], ak[it], acc_k, 0, 0, 0);

  // diag of K.K^T: D[m][n], m=quad*4+r, n=m16
#pragma unroll
  for (int r = 0; r < 4; r++) {
    if (m16 == quad * 4 + r) skmag[w * 16 + m16] = sqrtf(fmaxf(acc_k[r], 0.f));
  }
  __syncthreads();

#pragma unroll
  for (int h = 0; h < 16; h++) {
    const float km = skmag[w * 16 + h];
    const float v = (float)cp[1024 + h * 64 + lane];
    fieldb[((size_t)(b * 16 + h) * 2048 + n_pos) * 64 + lane] = (bf16_t)(v * km);
  }

  if (lane < 16) {
    const int head = lane;
    const bf16_t* lp = cp + 3072 + head * SS;
    float lg[SS];
    float mx = -1e30f;
#pragma unroll
    for (int s = 0; s < SS; s++) {
      lg[s] = (float)lp[s] + scale_gain[s * 16 + head];
      mx = fmaxf(mx, lg[s]);
    }
    float se = 0.f;
#pragma unroll
    for (int s = 0; s < SS; s++) { lg[s] = __expf(lg[s] - mx); se += lg[s]; }
    const float inv = 1.f / se;
    float* gp = gains + ((size_t)(b * 16 + head) * 2048 + n_pos) * SS;
#pragma unroll
    for (int s = 0; s < SS; s++) gp[s] = lg[s] * inv;
  }
}

// ---------------- multiscale causal D4 conv, offset-collapsed ----------------
__global__ __launch_bounds__(256) void conv_k(const bf16_t* __restrict__ field,
                                              const float* __restrict__ gains,
                                              bf16_t* __restrict__ facc) {
  __shared__ float sg[32 * SS];
  const int tid = threadIdx.x;
  const int blk = blockIdx.x;
  const int bh = blk & 63;
  const int ntile = blk >> 6;          // 0..63
  const int n0 = ntile * 32;

  for (int i = tid; i < 32 * SS; i += 256)
    sg[i] = gains[((size_t)bh * 2048 + n0) * SS + i];
  __syncthreads();

  const int w = tid >> 6, lane = tid & 63;
  const int nsub = lane >> 3, c = lane & 7;
  const int ln = w * 8 + nsub;         // 0..31
  const int n = n0 + ln;
  const bf16_t* frow = field + (size_t)bh * 2048 * 64;

  float g[SS];
#pragma unroll
  for (int s = 0; s < SS; s++) g[s] = sg[ln * SS + s];

  float acc[8];
  {
    bf16x8_t f0 = *(const bf16x8_t*)(frow + (size_t)n * 64 + c * 8);
#pragma unroll
    for (int q = 0; q < 8; q++) acc[q] = D4_3 * (float)f0[q];
  }
#pragma unroll
  for (int j = 0; j < 11; j++) {
    float wgt = D4_2 * g[j];
    if (j >= 1) wgt += D4_1 * g[j - 1];
    int rr = n - (1 << j);
    float wv = rr >= 0 ? wgt : 0.f;
    rr = rr >= 0 ? rr : 0;
    bf16x8_t fv = *(const bf16x8_t*)(frow + (size_t)rr * 64 + c * 8);
#pragma unroll
    for (int q = 0; q < 8; q++) acc[q] += wv * (float)fv[q];
  }
#pragma unroll
  for (int j = 0; j < 10; j++) {
    int rr = n - (3 << j);
    float wv = rr >= 0 ? (D4_0 * g[j]) : 0.f;
    rr = rr >= 0 ? rr : 0;
    bf16x8_t fv = *(const bf16x8_t*)(frow + (size_t)rr * 64 + c * 8);
#pragma unroll
    for (int q = 0; q < 8; q++) acc[q] += wv * (float)fv[q];
  }
  bf16x8_t o;
#pragma unroll
  for (int q = 0; q < 8; q++) o[q] = (bf16_t)acc[q];
  *(bf16x8_t*)(facc + ((size_t)bh * 2048 + n) * 64 + c * 8) = o;
}

// ---------------- head coupling softmax mix + gate (from C) + bf16 cast ----------------
__global__ __launch_bounds__(1024) void couple_gate_k(const bf16_t* __restrict__ facc,
                                                      const float* __restrict__ fcoup,
                                                      const bf16_t* __restrict__ C,
                                                      bf16_t* __restrict__ gmat) {
  __shared__ float sacc[1024];
  __shared__ float sc[256];
  __shared__ float scn[256];
  const int tid = threadIdx.x;
  const int bn = blockIdx.x;
  const int b = bn >> 11, n = bn & 2047;
  if (tid < 256) sc[tid] = fcoup[tid];
  const int i = tid >> 6, hd = tid & 63;
  sacc[tid] = (float)facc[(((size_t)(b * 16 + i)) * 2048 + n) * 64 + hd];
  __syncthreads();
  if (tid < 16) {
    float row[16];
    float mx = -1e30f;
#pragma unroll
    for (int j = 0; j < 16; j++) { row[j] = sc[tid * 16 + j]; mx = fmaxf(mx, row[j]); }
    float se = 0.f;
#pragma unroll
    for (int j = 0; j < 16; j++) { row[j] = __expf(row[j] - mx); se += row[j]; }
    float inv = 1.f / se;
#pragma unroll
    for (int j = 0; j < 16; j++) scn[tid * 16 + j] = row[j] * inv;
  }
  __syncthreads();
  float s = 0.f;
#pragma unroll
  for (int j = 0; j < 16; j++) s += scn[i * 16 + j] * sacc[j * 64 + hd];
  const float gt = (float)C[(size_t)bn * LDC + 2048 + tid];
  gmat[(size_t)bn * 1024 + tid] = (bf16_t)(s * gt);
}

// ---------------- launch ----------------
extern "C" void kernel_launch(void* const* d_in, const int* in_sizes, int n_in,
                              void* d_out, int out_size, void* d_ws, size_t ws_size,
                              hipStream_t stream) {
  (void)in_sizes; (void)n_in; (void)out_size; (void)ws_size;
  const float* x = (const float*)d_in[0];
  const float* Wqkv = (const float*)d_in[1];
  const float* bqkv = (const float*)d_in[2];
  const float* Wo = (const float*)d_in[3];
  const float* bo = (const float*)d_in[4];
  const float* Wg = (const float*)d_in[5];
  const float* bg = (const float*)d_in[6];
  const float* scale_gain = (const float*)d_in[7];
  const float* Wqs = (const float*)d_in[8];
  const float* fcoup = (const float*)d_in[9];

  char* ws = (char*)d_ws;
  size_t off = 0;
  auto alloc = [&](size_t bytes) {
    void* p = ws + off;
    off += (bytes + 255) & ~(size_t)255;
    return p;
  };
  bf16_t* xb = (bf16_t*)alloc(8192ull * 1024 * 2);       // 16 MB
  bf16_t* Wab = (bf16_t*)alloc(3328ull * 1024 * 2);      // 6.8 MB: [Wk|Wv|Wg|Wl+pad]
  bf16_t* Wob = (bf16_t*)alloc(1024ull * 1024 * 2);      // 2 MB
  float* biasA = (float*)alloc(3328ull * 4);             // [bk|bv|bg|bl+pad]
  bf16_t* C = (bf16_t*)alloc(8192ull * LDC * 2);         // 54.5 MB
  bf16_t* fieldb = (bf16_t*)alloc(8388608ull * 2);       // 16 MB
  float* gains = (float*)alloc(8192ull * 16 * SS * 4);   // 5.8 MB
  bf16_t* facc = (bf16_t*)alloc(8388608ull * 2);         // 16 MB
  bf16_t* gmat = (bf16_t*)alloc(8192ull * 1024 * 2);     // 16 MB

  // fused prologue: conversions + Wl fold + bias assembly
  prep_k<<<12305, 256, 0, stream>>>(x, Wqkv, Wqs, bqkv, Wg, Wo, bg, xb, Wab, Wob, biasA);

  // GEMM-A': C = xb * Wab^T + biasA (M=8192, N=3328, K=1024), mtile-fastest block order
  gemm_a<<<64 * 26, 256, 0, stream>>>(xb, Wab, biasA, C);

  // field + gains (MFMA kmag, reads C)
  field_gains_k<<<2048, 256, 0, stream>>>(C, scale_gain, fieldb, gains);

  // multiscale conv (blk low 6 bits = bh)
  conv_k<<<4096, 256, 0, stream>>>(fieldb, gains, facc);

  // coupling + gate
  couple_gate_k<<<8192, 1024, 0, stream>>>(facc, fcoup, C, gmat);

  // GEMM-B: output (M=8192, N=1024, K=1024), fp32 out
  gemm_b<<<64 * 8, 256, 0, stream>>>(gmat, Wob, bo, (float*)d_out, 8192, 1024, 1024);
}